// Round 8
// baseline (195.197 us; speedup 1.0000x reference)
//
#include <hip/hip_runtime.h>

#define NN 10000
#define EE 160000
#define ETOT (EE + NN)
#define EMB 768
#define ODIM 1024
#define NEG 0.2f
#define CAP 56          // max in/out degree ~45 (Binom(160k,1e-4) max + self-loop)

// ---- workspace layout (4B units) ----
#define OFF_PT     0          // 12288 : P transposed [j*768+k] (src j<8, dst j>=8)
#define OFF_Q      12288      // 8
#define OFF_EAACC  12296      // 1 (zeroed)
#define OFF_CNTD   12304      // int[10000] (zeroed)
#define OFF_CNTS   22304      // int[10000] (zeroed)
#define ZERO_START 12296
#define ZERO_CNT   20008
#define OFF_A      32304      // 10000*16 : a_src(0..7), a_dst(8..15)
#define OFF_EDD    192304     // int2[10000*CAP] : (e, src) per dst-bucket slot
#define OFF_EDS    1312304    // int2[10000*CAP] : (e, dst) per src-bucket slot
#define OFF_EX     2432304    // 170000*8 : exp vals, EDGE ORDER (coalesced)
#define OFF_RDEN   3792304    // 80000 : 1/denominator per (dst,h)
#define OFF_S      3872304    // 80000 : outgoing attention sums
#define OFF_Z      3952304    // 2*8*768
#define OFF_YPART  3964592    // 157*6144 : y partials [b][h*768+col]
// end 4929200 floats = 19.7 MB

// K1F: PT/Q precontract + edge_attr sum + bucket fill + bias-out init
__global__ __launch_bounds__(256) void k1f(
    const float* __restrict__ W, const float* __restrict__ att_src,
    const float* __restrict__ att_dst, const float* __restrict__ W_edge,
    const float* __restrict__ att_edge, const float* __restrict__ edge_attr,
    const int* __restrict__ ei, const float* __restrict__ bias,
    const float* __restrict__ clf_W, const float* __restrict__ clf_b,
    float* __restrict__ out, float* __restrict__ ws) {
  __shared__ float red[8];
  int b = blockIdx.x;
  int* wsI = (int*)ws;
  if (b < 48) {
    int tid = b * 256 + threadIdx.x;   // 0..12287
    int k = tid >> 4, j = tid & 15, h = j & 7;
    const float* att = (j < 8) ? att_src : att_dst;
    const float* wp = W + k * ODIM + h * 128;
    const float* ap = att + h * 128;
    float acc = 0.f;
    #pragma unroll 8
    for (int c = 0; c < 128; ++c) acc += wp[c] * ap[c];
    ws[OFF_PT + j * 768 + k] = acc;    // transposed for kAx
  } else if (b == 48) {
    if (threadIdx.x < 8) {
      int h = threadIdx.x;
      float acc = 0.f;
      #pragma unroll 8
      for (int c = 0; c < 128; ++c) acc += W_edge[h * 128 + c] * att_edge[h * 128 + c];
      ws[OFF_Q + h] = acc;
    }
  } else if (b < 113) {
    int bi = b - 49;   // 64 blocks: sum edge_attr
    float acc = 0.f;
    for (int i = bi * 256 + threadIdx.x; i < EE; i += 64 * 256) acc += edge_attr[i];
    #pragma unroll
    for (int off = 32; off > 0; off >>= 1) acc += __shfl_down(acc, off, 64);
    if ((threadIdx.x & 63) == 0) atomicAdd(&ws[OFF_EAACC], acc);
  } else if (b < 778) {
    int e = (b - 113) * 256 + threadIdx.x;
    if (e >= ETOT) return;
    int src, dst;
    if (e < EE) { src = ei[e]; dst = ei[EE + e]; } else { src = dst = e - EE; }
    int pd = atomicAdd(&wsI[OFF_CNTD + dst], 1);
    if (pd < CAP) ((int2*)(wsI + OFF_EDD))[dst * CAP + pd] = make_int2(e, src);
    int ps = atomicAdd(&wsI[OFF_CNTS + src], 1);
    if (ps < CAP) ((int2*)(wsI + OFF_EDS))[src * CAP + ps] = make_int2(e, dst);
  } else {
    // out = clf_b + sum_i bias[i&1023]*clf_W[i]  (k8 atomicAdds on top)
    int t = threadIdx.x;
    float b0 = 0.f, b1 = 0.f;
    for (int i = t; i < 3072; i += 256) {
      float f = bias[i & 1023];
      b0 += f * clf_W[2 * i];
      b1 += f * clf_W[2 * i + 1];
    }
    #pragma unroll
    for (int o = 32; o > 0; o >>= 1) {
      b0 += __shfl_down(b0, o, 64);
      b1 += __shfl_down(b1, o, 64);
    }
    if ((t & 63) == 0) { red[(t >> 6) * 2] = b0; red[(t >> 6) * 2 + 1] = b1; }
    __syncthreads();
    if (t == 0) {
      out[0] = clf_b[0] + red[0] + red[2] + red[4] + red[6];
      out[1] = clf_b[1] + red[1] + red[3] + red[5] + red[7];
    }
  }
}

// KAX: A = x @ P via PT in 48KB LDS; 16 nodes/block, ds_read_b128, 2-way banks
__global__ __launch_bounds__(256) void kAx(const float* __restrict__ x,
                                           float* __restrict__ ws) {
  __shared__ float sm[12288];
  for (int i = threadIdx.x; i < 3072; i += 256)
    ((float4*)sm)[i] = ((const float4*)(ws + OFF_PT))[i];
  __syncthreads();
  int li = threadIdx.x & 15, nl = threadIdx.x >> 4;
  int n = blockIdx.x * 16 + nl;      // 625*16 = 10000 exact
  float a[16];
  #pragma unroll
  for (int j = 0; j < 16; ++j) a[j] = 0.f;
  const float4* xr = (const float4*)(x + n * EMB);
  const float4* pT4 = (const float4*)sm;   // [j*192 + k4]
  for (int i = 0; i < 12; ++i) {
    float4 xv = xr[li + i * 16];
    int k4 = li + i * 16;
    #pragma unroll
    for (int j = 0; j < 16; ++j) {
      float4 p = pT4[j * 192 + k4];
      a[j] += xv.x * p.x + xv.y * p.y + xv.z * p.z + xv.w * p.w;
    }
  }
  __syncthreads();   // PT reads done; reuse sm for partials
  #pragma unroll
  for (int j = 0; j < 16; ++j) sm[threadIdx.x * 17 + j] = a[j];
  __syncthreads();
  int rn = threadIdx.x >> 4, rj = threadIdx.x & 15;
  float s = 0.f;
  #pragma unroll
  for (int c = 0; c < 16; ++c) s += sm[(rn * 16 + c) * 17 + rj];
  ws[OFF_A + (blockIdx.x * 16 + rn) * 16 + rj] = s;
}

// KE: edge-parallel exp -> EX in edge order (fully coalesced 32B/edge)
__global__ __launch_bounds__(256) void kE(const int* __restrict__ ei,
                                          const float* __restrict__ edge_attr,
                                          float* __restrict__ ws) {
  int e = blockIdx.x * 256 + threadIdx.x;
  if (e >= ETOT) return;
  int src, dst; float ea;
  if (e < EE) { src = ei[e]; dst = ei[EE + e]; ea = edge_attr[e]; }
  else { src = dst = e - EE; ea = ws[OFF_EAACC] * (1.0f / EE); }
  const float4* as4 = (const float4*)(ws + OFF_A + src * 16);
  const float4* ad4 = (const float4*)(ws + OFF_A + dst * 16 + 8);
  float4 s0 = as4[0], s1 = as4[1], d0 = ad4[0], d1 = ad4[1];
  float asr[8] = {s0.x, s0.y, s0.z, s0.w, s1.x, s1.y, s1.z, s1.w};
  float ads[8] = {d0.x, d0.y, d0.z, d0.w, d1.x, d1.y, d1.z, d1.w};
  float ex[8];
  #pragma unroll
  for (int h = 0; h < 8; ++h) {
    float v = asr[h] + ads[h] + ea * ws[OFF_Q + h];
    v = (v >= 0.f) ? v : NEG * v;
    ex[h] = __expf(v);
  }
  float4* p = (float4*)(ws + OFF_EX + e * 8);
  p[0] = make_float4(ex[0], ex[1], ex[2], ex[3]);
  p[1] = make_float4(ex[4], ex[5], ex[6], ex[7]);
}

// KD: rden per (dst,h): gather EX by edge-id from EDD buckets
__global__ __launch_bounds__(128) void kD(float* __restrict__ ws) {
  int t = blockIdx.x * 128 + threadIdx.x;   // 625*128 = 80000 exact
  int dst = t >> 3, h = t & 7;
  const int* wsI = (const int*)ws;
  int deg = wsI[OFF_CNTD + dst]; if (deg > CAP) deg = CAP;
  const int2* edd = (const int2*)(wsI + OFF_EDD) + dst * CAP;
  float den = 0.f;
  for (int j = 0; j < deg; ++j) den += ws[OFF_EX + edd[j].x * 8 + h];
  ws[OFF_RDEN + t] = 1.0f / den;
}

// KSZ: blocks 0..624: s per (src,h); blocks 625..636: z for text/image
__global__ __launch_bounds__(128) void kSZ(const float* __restrict__ x,
                                           const int* __restrict__ tptr,
                                           const int* __restrict__ iptr,
                                           float* __restrict__ ws) {
  __shared__ float sm[512];
  const int* wsI = (const int*)ws;
  if (blockIdx.x < 625) {
    int t = blockIdx.x * 128 + threadIdx.x;  // 0..79999
    int src = t >> 3, h = t & 7;
    int deg = wsI[OFF_CNTS + src]; if (deg > CAP) deg = CAP;
    const int2* eds = (const int2*)(wsI + OFF_EDS) + src * CAP;
    float s = 0.f;
    for (int j = 0; j < deg; ++j) {
      int2 ed = eds[j];
      s += ws[OFF_EX + ed.x * 8 + h] * ws[OFF_RDEN + ed.y * 8 + h];
    }
    ws[OFF_S + t] = s;
  } else {
    float* wL = sm;                 // [448]
    int* srcS = (int*)(sm + 448);   // [56]
    int* degP = (int*)(sm + 508);
    int r = blockIdx.x - 625;       // 0..11
    int d = r / 6, kc = r % 6;      // d: 0=text 1=image; kc: 128-col chunk
    int target = (d == 0) ? tptr[0] : iptr[0];
    if (threadIdx.x == 0) {
      int dg = wsI[OFF_CNTD + target];
      degP[0] = (dg > CAP) ? CAP : dg;
    }
    __syncthreads();
    int deg = degP[0];
    for (int idx = threadIdx.x; idx < deg * 8; idx += 128) {
      int j = idx >> 3, h = idx & 7;
      int2 ed = ((const int2*)(wsI + OFF_EDD))[target * CAP + j];
      wL[idx] = ws[OFF_EX + ed.x * 8 + h] * ws[OFF_RDEN + target * 8 + h];
      if (h == 0) srcS[j] = ed.y;
    }
    __syncthreads();
    int col = kc * 128 + threadIdx.x;
    float acc[8];
    #pragma unroll
    for (int h = 0; h < 8; ++h) acc[h] = 0.f;
    for (int j = 0; j < deg; ++j) {
      float xv = x[srcS[j] * EMB + col];
      const float* wv = &wL[j * 8];
      #pragma unroll
      for (int h = 0; h < 8; ++h) acc[h] += wv[h] * xv;
    }
    #pragma unroll
    for (int h = 0; h < 8; ++h) ws[OFF_Z + (d * 8 + h) * EMB + col] = acc[h];
  }
}

// K7S: y-partials: YPART[bx][h*768 + col] = sum over 64 nodes of s[n][h]*x[n][col]
__global__ __launch_bounds__(256) void k7s(const float* __restrict__ x,
                                           float* __restrict__ ws) {
  __shared__ float sL[64 * 8];
  int base = blockIdx.x * 64;
  int c = blockIdx.y;
  for (int i = threadIdx.x; i < 512; i += 256) {
    int n = base + (i >> 3);
    sL[i] = (n < NN) ? ws[OFF_S + base * 8 + i] : 0.f;
  }
  __syncthreads();
  int col = c * 256 + threadIdx.x;
  float acc[8];
  #pragma unroll
  for (int h = 0; h < 8; ++h) acc[h] = 0.f;
  int nmax = (NN - base < 64) ? (NN - base) : 64;
  for (int i = 0; i < nmax; ++i) {
    float xv = x[(base + i) * EMB + col];
    const float* sv = &sL[i * 8];
    #pragma unroll
    for (int h = 0; h < 8; ++h) acc[h] += xv * sv[h];
  }
  float* yp = ws + OFF_YPART + blockIdx.x * 6144 + col;
  #pragma unroll
  for (int h = 0; h < 8; ++h) yp[h * 768] = acc[h];
}

// K8: Y-reduce + projection + classifier dot -> atomicAdd into out
__global__ __launch_bounds__(128) void k8(const float* __restrict__ W,
                                          const float* __restrict__ clf_W,
                                          float* __restrict__ out,
                                          float* __restrict__ ws) {
  __shared__ float vL[144];
  __shared__ float red[4];
  int h = blockIdx.x, kc = blockIdx.y, kbase = kc * 48;
  for (int i = threadIdx.x; i < 144; i += 128) {
    int d = i / 48, k = i - d * 48;
    float v;
    if (d == 0) {
      float acc = 0.f;
      for (int b = 0; b < 157; ++b)
        acc += ws[OFF_YPART + b * 6144 + h * 768 + kbase + k];
      v = acc * (1.0f / NN);
    } else {
      v = ws[OFF_Z + ((d - 1) * 8 + h) * 768 + kbase + k];
    }
    vL[i] = v;
  }
  __syncthreads();
  int c = threadIdx.x;
  float a0 = 0.f, a1 = 0.f, a2 = 0.f;
  #pragma unroll 4
  for (int k = 0; k < 48; ++k) {
    float wv = W[(kbase + k) * ODIM + h * 128 + c];
    a0 += vL[k] * wv;
    a1 += vL[48 + k] * wv;
    a2 += vL[96 + k] * wv;
  }
  int ib = h * 128 + c;
  float l0 = a0 * clf_W[2 * ib] + a1 * clf_W[2 * (1024 + ib)]
           + a2 * clf_W[2 * (2048 + ib)];
  float l1 = a0 * clf_W[2 * ib + 1] + a1 * clf_W[2 * (1024 + ib) + 1]
           + a2 * clf_W[2 * (2048 + ib) + 1];
  #pragma unroll
  for (int o = 32; o > 0; o >>= 1) {
    l0 += __shfl_down(l0, o, 64);
    l1 += __shfl_down(l1, o, 64);
  }
  if ((threadIdx.x & 63) == 0) {
    red[(threadIdx.x >> 6) * 2] = l0;
    red[(threadIdx.x >> 6) * 2 + 1] = l1;
  }
  __syncthreads();
  if (threadIdx.x == 0) {
    atomicAdd(&out[0], red[0] + red[2]);
    atomicAdd(&out[1], red[1] + red[3]);
  }
}

extern "C" void kernel_launch(void* const* d_in, const int* in_sizes, int n_in,
                              void* d_out, int out_size, void* d_ws, size_t ws_size,
                              hipStream_t stream) {
  const float* x        = (const float*)d_in[0];
  const int*   ei       = (const int*)d_in[1];
  const float* edge_attr= (const float*)d_in[2];
  const int*   tptr     = (const int*)d_in[3];
  const int*   iptr     = (const int*)d_in[4];
  const float* W        = (const float*)d_in[5];
  const float* att_src  = (const float*)d_in[6];
  const float* att_dst  = (const float*)d_in[7];
  const float* W_edge   = (const float*)d_in[8];
  const float* att_edge = (const float*)d_in[9];
  const float* bias     = (const float*)d_in[10];
  const float* clf_W    = (const float*)d_in[11];
  const float* clf_b    = (const float*)d_in[12];
  float* ws  = (float*)d_ws;
  float* out = (float*)d_out;

  hipMemsetAsync(ws + ZERO_START, 0, ZERO_CNT * sizeof(float), stream);
  k1f<<<779, 256, 0, stream>>>(W, att_src, att_dst, W_edge, att_edge, edge_attr,
                               ei, bias, clf_W, clf_b, out, ws);
  kAx<<<625, 256, 0, stream>>>(x, ws);
  kE<<<665, 256, 0, stream>>>(ei, edge_attr, ws);
  kD<<<625, 128, 0, stream>>>(ws);
  kSZ<<<637, 128, 0, stream>>>(x, tptr, iptr, ws);
  dim3 g7(157, 3);
  k7s<<<g7, 256, 0, stream>>>(x, ws);
  dim3 g8(8, 16);
  k8<<<g8, 128, 0, stream>>>(W, clf_W, out, ws);
}